// Round 12
// baseline (559.213 us; speedup 1.0000x reference)
//
#include <hip/hip_runtime.h>

#define SS  128
#define DD  512
#define NHH 8
#define DHH 64

typedef float  f4 __attribute__((ext_vector_type(4)));
typedef float  f2 __attribute__((ext_vector_type(2)));
typedef double d2 __attribute__((ext_vector_type(2)));

typedef const void __attribute__((address_space(1)))* gas_t;
typedef void __attribute__((address_space(3)))* las_t;

// ================= K1: q[b,o] = x_non[b] . Wq[o,:] + bq[o]  (f64 acc) =========
// (verified; unchanged)
__global__ __launch_bounds__(512) void qproj_kernel(
    const float* __restrict__ x_non, const float* __restrict__ Wq,
    const float* __restrict__ bq, double* __restrict__ qws)
{
    const int tid = threadIdx.x;
    const int bt  = blockIdx.x & 31;
    const int ot  = blockIdx.x >> 5;
    const int kh  = tid >> 8;            // K-half (wave-uniform)
    const int t8  = tid & 255;
    const int r   = t8 >> 4, c = t8 & 15;

    __shared__ __attribute__((aligned(16))) float Xs0[32][68];
    __shared__ __attribute__((aligned(16))) float Xs1[32][68];
    __shared__ __attribute__((aligned(16))) float Ws0[64][68];
    __shared__ __attribute__((aligned(16))) float Ws1[64][68];

    double acc[2][4];
    #pragma unroll
    for (int i = 0; i < 2; ++i)
        #pragma unroll
        for (int j = 0; j < 4; ++j) acc[i][j] = 0.0;

    for (int kc = 0; kc < 4; ++kc) {
        __syncthreads();
        #pragma unroll
        for (int p = 0; p < 2; ++p) {
            int g  = tid + 512 * p;
            int rr = g >> 5, w = g & 31, hf = w >> 4, cc = (w & 15) * 4;
            f4 v = *(const f4*)(x_non + (size_t)(bt * 32 + rr) * DD + hf * 256 + kc * 64 + cc);
            if (hf) *(f4*)&Xs1[rr][cc] = v; else *(f4*)&Xs0[rr][cc] = v;
        }
        #pragma unroll
        for (int p = 0; p < 4; ++p) {
            int g  = tid + 512 * p;
            int rr = g >> 5, w = g & 31, hf = w >> 4, cc = (w & 15) * 4;
            f4 v = *(const f4*)(Wq + (size_t)(ot * 64 + rr) * DD + hf * 256 + kc * 64 + cc);
            if (hf) *(f4*)&Ws1[rr][cc] = v; else *(f4*)&Ws0[rr][cc] = v;
        }
        __syncthreads();
        const float (*Xh)[68] = kh ? Xs1 : Xs0;
        const float (*Wh)[68] = kh ? Ws1 : Ws0;
        #pragma unroll 4
        for (int kk = 0; kk < 64; ++kk) {
            double a0 = (double)Xh[r][kk];
            double a1 = (double)Xh[r + 16][kk];
            #pragma unroll
            for (int j = 0; j < 4; ++j) {
                double bb = (double)Wh[c + 16 * j][kk];
                acc[0][j] = fma(a0, bb, acc[0][j]);
                acc[1][j] = fma(a1, bb, acc[1][j]);
            }
        }
    }
    __syncthreads();
    double* S = (double*)&Ws0[0][0];
    if (kh == 1) {
        #pragma unroll
        for (int i = 0; i < 2; ++i)
            #pragma unroll
            for (int j = 0; j < 4; ++j) S[t8 * 8 + i * 4 + j] = acc[i][j];
    }
    __syncthreads();
    if (kh == 0) {
        #pragma unroll
        for (int i = 0; i < 2; ++i)
            #pragma unroll
            for (int j = 0; j < 4; ++j) {
                int o = ot * 64 + c + 16 * j;
                qws[(size_t)(bt * 32 + r + 16 * i) * DD + o] =
                    acc[i][j] + S[t8 * 8 + i * 4 + j] + (double)bq[o];
            }
    }
}

// ---- async stage: one 8-row (16 KB) chunk of X into LDS, linear layout -------
__device__ __forceinline__ void stage_chunk(const float* __restrict__ Xb,
                                            int c, int tid, float* XsF)
{
    const int wid  = tid >> 6;
    const int lane = tid & 63;
    const float* gsrc = Xb + (size_t)c * (8 * DD);
    #pragma unroll
    for (int p = 0; p < 4; ++p) {
        const int gbase = p * 256 + wid * 64;             // 16B-granule index base
        const float* gp = gsrc + (size_t)(gbase + lane) * 4;
        float* lp = XsF + (size_t)gbase * 4;              // wave-uniform dest
        __builtin_amdgcn_global_load_lds((gas_t)gp, (las_t)lp, 16, 0, 0);
    }
}

// ================= K2: per-(b, head-group) attention core =====================
// v12: head-split. Grid 2048 = b(1024) x head-half(2); wave = ONE head.
// - treg computed DIRECTLY from global Wk (T LDS eliminated; Wk is L2-hot)
// - Xs single-buffered 16 KB -> LDS ~20.5 KB -> 6-7 blocks/CU (was 4)
// - per-(head,row) softmax sequence identical to the verified round-1 kernel
// - b = blockIdx & 1023 so twin blocks (b, b+1024) map to the same XCD (RR)
__global__ __launch_bounds__(256) void core_kernel(
    const double* __restrict__ qws, const float* __restrict__ x_seq,
    const int* __restrict__ mask, const float* __restrict__ Wk,
    const float* __restrict__ bk, float* __restrict__ uws)
{
    const int tid  = threadIdx.x;
    const int b    = blockIdx.x & 1023;
    const int hgrp = (blockIdx.x >> 10) * 4;   // heads hgrp .. hgrp+3
    const float* Xb = x_seq + (size_t)b * (SS * DD);

    const int hp    = tid >> 6;        // wave id 0..3
    const int h     = hgrp + hp;       // this wave's head (global 0..7)
    const int rhalf = (tid >> 5) & 1;  // chunk row half (rows rhalf*4 .. +4)
    const int k16   = tid & 31;        // 16-col group: cols {k16*2 + 64p}

    __shared__ __attribute__((aligned(16))) float Xs[8][512];   // 16 KB, single buffer
    __shared__ __attribute__((aligned(16))) union {
        double qd[512];                // q[b] (pre-flash only)
        int    mk[1024];               // mask[b] (flash)
    } sh2;
    __shared__ double qbks[8];

    // ---- load q[b] (f64, coalesced) ----
    sh2.qd[tid]       = qws[(size_t)b * DD + tid];
    sh2.qd[tid + 256] = qws[(size_t)b * DD + tid + 256];
    __syncthreads();

    // ---- qbk[h] = q_h . bk_h (wave 0, 8 lanes per head; unchanged) ----
    if (tid < 64) {
        const int hh = tid >> 3, part = tid & 7;
        double s = 0.0;
        #pragma unroll
        for (int ii = 0; ii < 8; ++ii) {
            int d = part * 8 + ii;
            s = fma(sh2.qd[hh * DHH + d], (double)bk[hh * DHH + d], s);
        }
        s += __shfl_xor(s, 1);
        s += __shfl_xor(s, 2);
        s += __shfl_xor(s, 4);
        if (part == 0) qbks[hh] = s;
    }

    // ---- treg[p] = t[h][k16*2 + 64p .. +2], computed directly from global Wk.
    // Per d: 8 independent f2 loads (wave-broadcast addresses; Wk L2-hot).
    // f64 accumulation order d=0..63 (vs old split-halves: diff ~1e-16).
    d2 treg[8];
    #pragma unroll
    for (int p = 0; p < 8; ++p) { treg[p][0] = 0.0; treg[p][1] = 0.0; }
    {
        const float* wkh = Wk + (size_t)(h * DHH) * DD + k16 * 2;
        for (int d = 0; d < DHH; ++d) {
            const double qv = sh2.qd[h * DHH + d];
            const float* wr = wkh + (size_t)d * DD;
            #pragma unroll
            for (int p = 0; p < 8; ++p) {
                f2 wv = *(const f2*)(wr + p * 64);
                treg[p][0] = fma((double)wv[0], qv, treg[p][0]);
                treg[p][1] = fma((double)wv[1], qv, treg[p][1]);
            }
        }
    }
    __syncthreads();                   // qd reads done; qbks ready

    const float qbkf = (float)qbks[h];

    // ---- stage mask[b] (overwrites qd space; visibility via loop barriers) ----
    #pragma unroll
    for (int p = 0; p < 4; ++p)
        sh2.mk[tid + 256 * p] = mask[(size_t)b * (NHH * SS) + tid + 256 * p];

    // ---- flash loop over 16 chunks of 8 rows (single-buffered) ----
    float u[16];
    #pragma unroll
    for (int j = 0; j < 16; ++j) u[j] = 0.f;
    float m_run = -1e30f;
    float l_run = 0.f;

    for (int c = 0; c < 16; ++c) {
        __syncthreads();               // all waves done reading Xs (and mk stores done)
        stage_chunk(Xb, c, tid, &Xs[0][0]);
        asm volatile("s_waitcnt vmcnt(0)");
        __syncthreads();               // chunk + mask visible to all

        const float* Xc = &Xs[0][0] + (rhalf * 4) * DD + k16 * 2;

        // qk partials over this thread's 16 columns (f64, preserves floor)
        double acc[4];
        #pragma unroll
        for (int r = 0; r < 4; ++r) acc[r] = 0.0;

        #pragma unroll
        for (int r = 0; r < 4; ++r) {
            #pragma unroll
            for (int p = 0; p < 8; ++p) {
                f2 xv = *(const f2*)&Xc[r * DD + p * 64];
                acc[r] = fma((double)xv[0], treg[p][0], acc[r]);
                acc[r] = fma((double)xv[1], treg[p][1], acc[r]);
            }
        }

        // reduce across the 32 k16-lanes; finish logits for own rows
        float Lown[4];
        #pragma unroll
        for (int r = 0; r < 4; ++r) {
            float s = (float)acc[r];
            s += __shfl_xor(s, 1);
            s += __shfl_xor(s, 2);
            s += __shfl_xor(s, 4);
            s += __shfl_xor(s, 8);
            s += __shfl_xor(s, 16);
            s = floorf((s + qbkf) * 0.125f);
            const int row = c * 8 + rhalf * 4 + r;
            if (sh2.mk[h * SS + row] == 0) s = -1e9f;
            Lown[r] = s;
        }

        // online softmax update (identical structure to verified kernel)
        float Loth[4];
        #pragma unroll
        for (int r = 0; r < 4; ++r) Loth[r] = __shfl_xor(Lown[r], 32);
        float cmax = fmaxf(
            fmaxf(fmaxf(Lown[0], Lown[1]), fmaxf(Lown[2], Lown[3])),
            fmaxf(fmaxf(Loth[0], Loth[1]), fmaxf(Loth[2], Loth[3])));
        float mnew = fmaxf(m_run, cmax);
        if (mnew != m_run) {
            float fs = __expf(m_run - mnew);
            #pragma unroll
            for (int j = 0; j < 16; ++j) u[j] *= fs;
            l_run *= fs;
            m_run = mnew;
        }
        float pw[4];
        float ps = 0.f;
        #pragma unroll
        for (int r = 0; r < 4; ++r) { pw[r] = __expf(Lown[r] - mnew); ps += pw[r]; }
        #pragma unroll
        for (int r = 0; r < 4; ++r) ps += __expf(Loth[r] - mnew);
        l_run += ps;

        // u += p * X over own rows (f32)
        #pragma unroll
        for (int r = 0; r < 4; ++r) {
            #pragma unroll
            for (int p = 0; p < 8; ++p) {
                f2 xv = *(const f2*)&Xc[r * DD + p * 64];
                u[p * 2]     = fmaf(pw[r], xv[0], u[p * 2]);
                u[p * 2 + 1] = fmaf(pw[r], xv[1], u[p * 2 + 1]);
            }
        }
    }

    // ---- merge row-halves, normalize, write u' (l_run/m_run are wave-uniform) ----
    #pragma unroll
    for (int j = 0; j < 16; ++j) u[j] += __shfl_xor(u[j], 32);

    if (rhalf == 0) {
        const float inv = 1.0f / l_run;
        float* dst = uws + ((size_t)b * NHH + h) * DD + k16 * 2;
        #pragma unroll
        for (int p = 0; p < 8; ++p) {
            f2 v;
            v[0] = u[p * 2]     * inv;
            v[1] = u[p * 2 + 1] * inv;
            *(f2*)&dst[p * 64] = v;
        }
    }
}

// ================= K3: z[b, h*64+j] = u'[b,h,:] . Wv[o,:] + bv[o]  (f32) ======
// (verified; unchanged)
__global__ __launch_bounds__(512) void zout_kernel(
    const float* __restrict__ uws, const float* __restrict__ Wv,
    const float* __restrict__ bv, float* __restrict__ out)
{
    const int tid = threadIdx.x;
    const int bt  = blockIdx.x & 31;
    const int ot  = blockIdx.x >> 5;          // == head h
    const int kh  = tid >> 8;
    const int t8  = tid & 255;
    const int r   = t8 >> 4, c = t8 & 15;

    __shared__ __attribute__((aligned(16))) float Us0[32][68];
    __shared__ __attribute__((aligned(16))) float Us1[32][68];
    __shared__ __attribute__((aligned(16))) float Ws0[64][68];
    __shared__ __attribute__((aligned(16))) float Ws1[64][68];

    float acc[2][4];
    #pragma unroll
    for (int i = 0; i < 2; ++i)
        #pragma unroll
        for (int j = 0; j < 4; ++j) acc[i][j] = 0.f;

    for (int kc = 0; kc < 4; ++kc) {
        __syncthreads();
        #pragma unroll
        for (int p = 0; p < 2; ++p) {
            int g  = tid + 512 * p;
            int rr = g >> 5, w = g & 31, hf = w >> 4, cc = (w & 15) * 4;
            f4 v = *(const f4*)(uws + ((size_t)(bt * 32 + rr) * NHH + ot) * DD
                                + hf * 256 + kc * 64 + cc);
            if (hf) *(f4*)&Us1[rr][cc] = v; else *(f4*)&Us0[rr][cc] = v;
        }
        #pragma unroll
        for (int p = 0; p < 4; ++p) {
            int g  = tid + 512 * p;
            int rr = g >> 5, w = g & 31, hf = w >> 4, cc = (w & 15) * 4;
            f4 v = *(const f4*)(Wv + (size_t)(ot * 64 + rr) * DD + hf * 256 + kc * 64 + cc);
            if (hf) *(f4*)&Ws1[rr][cc] = v; else *(f4*)&Ws0[rr][cc] = v;
        }
        __syncthreads();
        const float (*Uh)[68] = kh ? Us1 : Us0;
        const float (*Wh)[68] = kh ? Ws1 : Ws0;
        #pragma unroll 4
        for (int kk = 0; kk < 64; ++kk) {
            float a0 = Uh[r][kk];
            float a1 = Uh[r + 16][kk];
            #pragma unroll
            for (int j = 0; j < 4; ++j) {
                float bb = Wh[c + 16 * j][kk];
                acc[0][j] = fmaf(a0, bb, acc[0][j]);
                acc[1][j] = fmaf(a1, bb, acc[1][j]);
            }
        }
    }
    __syncthreads();
    float* S = (float*)&Ws0[0][0];
    if (kh == 1) {
        #pragma unroll
        for (int i = 0; i < 2; ++i)
            #pragma unroll
            for (int j = 0; j < 4; ++j) S[t8 * 8 + i * 4 + j] = acc[i][j];
    }
    __syncthreads();
    if (kh == 0) {
        #pragma unroll
        for (int i = 0; i < 2; ++i)
            #pragma unroll
            for (int j = 0; j < 4; ++j) {
                int o = ot * 64 + c + 16 * j;
                out[(size_t)(bt * 32 + r + 16 * i) * DD + o] =
                    acc[i][j] + S[t8 * 8 + i * 4 + j] + bv[o];
            }
    }
}

extern "C" void kernel_launch(void* const* d_in, const int* in_sizes, int n_in,
                              void* d_out, int out_size, void* d_ws, size_t ws_size,
                              hipStream_t stream) {
    const float* x_non = (const float*)d_in[0];
    const float* x_seq = (const float*)d_in[1];
    const int*   mask  = (const int*)d_in[2];
    const float* Wq    = (const float*)d_in[3];
    const float* bq    = (const float*)d_in[4];
    const float* Wk    = (const float*)d_in[5];
    const float* bk    = (const float*)d_in[6];
    const float* Wv    = (const float*)d_in[7];
    const float* bv    = (const float*)d_in[8];
    float*       out   = (float*)d_out;

    double* qws = (double*)d_ws;                                     // 4 MB
    float*  uws = (float*)((char*)d_ws + (size_t)1024 * DD * 8);     // 16 MB

    qproj_kernel<<<256, 512, 0, stream>>>(x_non, Wq, bq, qws);
    core_kernel<<<2048, 256, 0, stream>>>(qws, x_seq, mask, Wk, bk, uws);
    zout_kernel<<<256, 512, 0, stream>>>(uws, Wv, bv, out);
}